// Round 5
// baseline (1948.212 us; speedup 1.0000x reference)
//
#include <hip/hip_runtime.h>

#define TT 512
#define BB 1024
#define XD 24
#define ZD 16

typedef __attribute__((ext_vector_type(4))) _Float16 half4;
typedef __attribute__((ext_vector_type(4))) float f32x4;
typedef unsigned long long u64;

__device__ __forceinline__ f32x4 MFMA16(half4 a, half4 b, f32x4 c) {
#if defined(__HIP_DEVICE_COMPILE__)
    return __builtin_amdgcn_mfma_f32_16x16x16f16(a, b, c, 0, 0, 0);
#else
    return c;   // host pass only needs to parse
#endif
}

__device__ __forceinline__ f32x4 Z4() { return (f32x4){0.f, 0.f, 0.f, 0.f}; }

__device__ __forceinline__ float sigm(float x) { return 1.0f / (1.0f + __expf(-x)); }

// tanh via 1 - 2/(1+e^{2x}); saturates correctly through inf/rcp
__device__ __forceinline__ float tanh_fast(float x) {
    return 1.0f - 2.0f / (1.0f + __expf(2.0f * x));
}

__device__ __forceinline__ float softplus_f(float x) {
    return fmaxf(x, 0.0f) + log1pf(__expf(-fabsf(x)));
}

// A-fragment of W^T (16 out-feats x 16 k) for 16x16x16 f16 MFMA.
// Lane l holds W[k0+(l>>4)*4+j][o0+(l&15)], zero-padded outside Kreal/Nreal.
__device__ __forceinline__ half4 ldw(const float* W, int N, int Kreal, int Nreal,
                                     int k0, int o0, int lane) {
    int col = o0 + (lane & 15);
    int kb = k0 + ((lane >> 4) << 2);
    half4 r;
#pragma unroll
    for (int j = 0; j < 4; ++j) {
        int k = kb + j;
        float v = (k < Kreal && col < Nreal) ? W[(size_t)k * N + col] : 0.0f;
        r[j] = (_Float16)v;
    }
    return r;
}

__device__ __forceinline__ half4 cvt_relu(f32x4 a) {
    half4 r;
#pragma unroll
    for (int q = 0; q < 4; ++q) r[q] = (_Float16)fmaxf(a[q], 0.0f);
    return r;
}

__device__ __forceinline__ half4 cvt4(f32x4 a) {
    half4 r;
#pragma unroll
    for (int q = 0; q < 4; ++q) r[q] = (_Float16)a[q];
    return r;
}

__device__ __forceinline__ f32x4 ldb4(const float* b, int o, int lgr) {
    return *reinterpret_cast<const f32x4*>(b + o * 16 + lgr * 4);
}

__device__ __forceinline__ u64 h2u(half4 h) {
    union { half4 h; u64 u; } c; c.h = h; return c.u;
}
__device__ __forceinline__ half4 u2h(u64 u) {
    union { half4 h; u64 u; } c; c.u = u; return c.h;
}

__global__ __launch_bounds__(256, 1) void vrnn_kernel(
    const float* __restrict__ src, const float* __restrict__ eps,
    const float* __restrict__ Wx1, const float* __restrict__ bx1,
    const float* __restrict__ Wx2, const float* __restrict__ bx2,
    const float* __restrict__ Wz,  const float* __restrict__ bz,
    const float* __restrict__ We1, const float* __restrict__ be1,
    const float* __restrict__ We2, const float* __restrict__ be2,
    const float* __restrict__ Wem, const float* __restrict__ bem,
    const float* __restrict__ Wes, const float* __restrict__ bes,
    const float* __restrict__ Wih, const float* __restrict__ Whh,
    const float* __restrict__ Wf1, const float* __restrict__ bf1,
    const float* __restrict__ Wf2, const float* __restrict__ bf2,
    const float* __restrict__ Wf3, const float* __restrict__ bf3,
    float* __restrict__ out)
{
    // LDS-resident weight fragments (8B per lane per frag) — written once, never remat'd
    __shared__ u64 W1L[60 * 64];   // w1: we1 o*8+kt | we2 32+o*4+kt | wem 48+kt | wes 52+kt | wz 56+o
    __shared__ u64 W2L[24 * 64];   // w2: wx1 o*2+k2 | wx2 8+o*4+kt
    __shared__ u64 PXB[2][256];    // phi_x frags (double-buffered)
    __shared__ u64 PZB[256];       // phi_z frags
    __shared__ u64 HBUF[256];      // h frags
    __shared__ f32x4 RBUF[256];    // r gate (post-sigm)
    __shared__ f32x4 UBUF[256];    // u gate (post-sigm)

    const int tid = threadIdx.x;
    const int wid = tid >> 6;
    const int lane = tid & 63;
    const int lcol = lane & 15;
    const int lgr = lane >> 4;
    const int r0 = blockIdx.x * 16;

    if (wid == 0) {
        // ============ wave 0: u-gate (z-slot of r,z,n order), weights in regs ==========
        half4 wihU[4][8], whhU[4][4];
#pragma unroll
        for (int o = 0; o < 4; ++o) {
#pragma unroll
            for (int kt = 0; kt < 8; ++kt) wihU[o][kt] = ldw(Wih, 192, 128, 192, kt * 16, 64 + o * 16, lane);
#pragma unroll
            for (int kt = 0; kt < 4; ++kt) whhU[o][kt] = ldw(Whh, 192, 64, 192, kt * 16, 64 + o * 16, lane);
        }
        __syncthreads();   // pre-loop

#pragma unroll 1
        for (int t = 0; t < TT; ++t) {
            half4 hb[4];
#pragma unroll
            for (int kt = 0; kt < 4; ++kt) hb[kt] = u2h(HBUF[kt * 64 + lane]);
            f32x4 ga[4];
#pragma unroll
            for (int o = 0; o < 4; ++o) {
                f32x4 a = MFMA16(whhU[o][1], hb[1], MFMA16(whhU[o][0], hb[0], Z4()));
                f32x4 b = MFMA16(whhU[o][3], hb[3], MFMA16(whhU[o][2], hb[2], Z4()));
                ga[o] = a + b;
            }
            __syncthreads();   // B
            half4 pb[8];
#pragma unroll
            for (int kt = 0; kt < 4; ++kt) pb[kt] = u2h(PXB[t & 1][kt * 64 + lane]);
#pragma unroll
            for (int kt = 0; kt < 4; ++kt) pb[4 + kt] = u2h(PZB[kt * 64 + lane]);
#pragma unroll
            for (int o = 0; o < 4; ++o) {
                f32x4 a = ga[o];
#pragma unroll
                for (int kt = 0; kt < 4; ++kt) a = MFMA16(wihU[o][kt], pb[kt], a);
                f32x4 b = Z4();
#pragma unroll
                for (int kt = 0; kt < 4; ++kt) b = MFMA16(wihU[o][4 + kt], pb[4 + kt], b);
                f32x4 s = a + b;
                f32x4 uv;
#pragma unroll
                for (int q = 0; q < 4; ++q) uv[q] = sigm(s[q]);
                UBUF[o * 64 + lane] = uv;
            }
            __syncthreads();   // C
            __syncthreads();   // D
        }

    } else if (wid == 1) {
        // ============ wave 1: enc chain s3..s6 + z + phi_z (weights in LDS) ============
#pragma unroll
        for (int o = 0; o < 4; ++o) {
#pragma unroll
            for (int kt = 0; kt < 8; ++kt)
                W1L[(o * 8 + kt) * 64 + lane] = h2u(ldw(We1, 64, 128, 64, kt * 16, o * 16, lane));
#pragma unroll
            for (int kt = 0; kt < 4; ++kt)
                W1L[(32 + o * 4 + kt) * 64 + lane] = h2u(ldw(We2, 64, 64, 64, kt * 16, o * 16, lane));
            W1L[(56 + o) * 64 + lane] = h2u(ldw(Wz, 64, 16, 64, 0, o * 16, lane));
        }
#pragma unroll
        for (int kt = 0; kt < 4; ++kt) {
            W1L[(48 + kt) * 64 + lane] = h2u(ldw(Wem, 16, 64, 16, kt * 16, 0, lane));
            W1L[(52 + kt) * 64 + lane] = h2u(ldw(Wes, 16, 64, 16, kt * 16, 0, lane));
        }
        f32x4 BE1[4], BE2[4], BZ[4];
#pragma unroll
        for (int o = 0; o < 4; ++o) {
            BE1[o] = ldb4(be1, o, lgr);
            BE2[o] = ldb4(be2, o, lgr);
            BZ[o] = ldb4(bz, o, lgr);
        }
        f32x4 BM = ldb4(bem, 0, lgr), BS = ldb4(bes, 0, lgr);

        const float* eb_ = eps + (size_t)(r0 + lcol) * TT * ZD;
        f32x4 fe = *reinterpret_cast<const f32x4*>(eb_ + lgr * 4);

        f32x4 pzlast[4];
        half4 pzb[4];
        __syncthreads();   // pre-loop

#pragma unroll 1
        for (int t = 0; t < TT; ++t) {
            int zz = 0;
            asm volatile("" : "+v"(zz));   // defeat LICM of LDS weight reads
            const int la = lane + zz;

            half4 hb[4], pxb[4];
#pragma unroll
            for (int kt = 0; kt < 4; ++kt) hb[kt] = u2h(HBUF[kt * 64 + lane]);
#pragma unroll
            for (int kt = 0; kt < 4; ++kt) pxb[kt] = u2h(PXB[t & 1][kt * 64 + lane]);

            half4 a1b[4], enb[4];
#pragma unroll
            for (int o = 0; o < 4; ++o) {
                f32x4 a = BE1[o];
#pragma unroll
                for (int kt = 0; kt < 4; ++kt) a = MFMA16(u2h(W1L[(o * 8 + kt) * 64 + la]), pxb[kt], a);
                f32x4 b = Z4();
#pragma unroll
                for (int kt = 0; kt < 4; ++kt) b = MFMA16(u2h(W1L[(o * 8 + 4 + kt) * 64 + la]), hb[kt], b);
                a1b[o] = cvt_relu(a + b);
            }
#pragma unroll
            for (int o = 0; o < 4; ++o) {
                f32x4 a = MFMA16(u2h(W1L[(32 + o * 4 + 1) * 64 + la]), a1b[1],
                          MFMA16(u2h(W1L[(32 + o * 4 + 0) * 64 + la]), a1b[0], BE2[o]));
                f32x4 b = MFMA16(u2h(W1L[(32 + o * 4 + 3) * 64 + la]), a1b[3],
                          MFMA16(u2h(W1L[(32 + o * 4 + 2) * 64 + la]), a1b[2], Z4()));
                enb[o] = cvt_relu(a + b);
            }
            f32x4 am = MFMA16(u2h(W1L[(48 + 1) * 64 + la]), enb[1],
                       MFMA16(u2h(W1L[(48 + 0) * 64 + la]), enb[0], BM));
            f32x4 am2 = MFMA16(u2h(W1L[(48 + 3) * 64 + la]), enb[3],
                        MFMA16(u2h(W1L[(48 + 2) * 64 + la]), enb[2], Z4()));
            f32x4 as_ = MFMA16(u2h(W1L[(52 + 1) * 64 + la]), enb[1],
                        MFMA16(u2h(W1L[(52 + 0) * 64 + la]), enb[0], BS));
            f32x4 as2 = MFMA16(u2h(W1L[(52 + 3) * 64 + la]), enb[3],
                        MFMA16(u2h(W1L[(52 + 2) * 64 + la]), enb[2], Z4()));
            f32x4 eC = fe;
            if (t + 1 < TT) fe = *reinterpret_cast<const f32x4*>(eb_ + (size_t)(t + 1) * ZD + lgr * 4);
            f32x4 zD;
#pragma unroll
            for (int q = 0; q < 4; ++q)
                zD[q] = eC[q] * softplus_f(as_[q] + as2[q]) + (am[q] + am2[q]);
            half4 zb = cvt4(zD);
#pragma unroll
            for (int o = 0; o < 4; ++o) {
                f32x4 a = MFMA16(u2h(W1L[(56 + o) * 64 + la]), zb, BZ[o]);
                if (t == TT - 1) {
#pragma unroll
                    for (int q = 0; q < 4; ++q) pzlast[o][q] = fmaxf(a[q], 0.0f);
                }
                pzb[o] = cvt_relu(a);
                PZB[o * 64 + lane] = h2u(pzb[o]);
            }
            __syncthreads();   // B
            __syncthreads();   // C
            __syncthreads();   // D
        }

        // head on phi_z(T-1)
        half4 wf1t[4][4], wf2t[2][4], wf3t[2];
#pragma unroll
        for (int o = 0; o < 4; ++o)
#pragma unroll
            for (int kt = 0; kt < 4; ++kt) wf1t[o][kt] = ldw(Wf1, 64, 64, 64, kt * 16, o * 16, lane);
#pragma unroll
        for (int o = 0; o < 2; ++o)
#pragma unroll
            for (int kt = 0; kt < 4; ++kt) wf2t[o][kt] = ldw(Wf2, 32, 64, 32, kt * 16, o * 16, lane);
        wf3t[0] = ldw(Wf3, 1, 32, 1, 0, 0, lane);
        wf3t[1] = ldw(Wf3, 1, 32, 1, 16, 0, lane);
        f32x4 FB1[4], FB2[2];
#pragma unroll
        for (int o = 0; o < 4; ++o) FB1[o] = ldb4(bf1, o, lgr);
#pragma unroll
        for (int o = 0; o < 2; ++o) FB2[o] = ldb4(bf2, o, lgr);

        half4 o1b[4];
#pragma unroll
        for (int o = 0; o < 4; ++o) {
            f32x4 a = FB1[o];
#pragma unroll
            for (int kt = 0; kt < 4; ++kt) a = MFMA16(wf1t[o][kt], pzb[kt], a);
            o1b[o] = cvt_relu(a);
        }
        half4 o2b[2];
#pragma unroll
        for (int o = 0; o < 2; ++o) {
            f32x4 a = FB2[o];
#pragma unroll
            for (int kt = 0; kt < 4; ++kt) a = MFMA16(wf2t[o][kt], o1b[kt], a);
            o2b[o] = cvt_relu(a);
        }
        float b3 = bf3[0];
        f32x4 p = (f32x4){b3, b3, b3, b3};
        p = MFMA16(wf3t[0], o2b[0], p);
        p = MFMA16(wf3t[1], o2b[1], p);
        if (lgr == 0) out[r0 + lcol] = p[0];

        float* po = out + BB + (size_t)(r0 + lcol) * 64;
#pragma unroll
        for (int o = 0; o < 4; ++o)
            *reinterpret_cast<f32x4*>(po + o * 16 + lgr * 4) = pzlast[o];

    } else if (wid == 2) {
        // ============ wave 2: r-gate (regs) + phi_x chain (LDS weights) + x prefetch ===
        half4 wihR[4][8], whhR[4][4];
#pragma unroll
        for (int o = 0; o < 4; ++o) {
#pragma unroll
            for (int kt = 0; kt < 8; ++kt) wihR[o][kt] = ldw(Wih, 192, 128, 192, kt * 16, o * 16, lane);
#pragma unroll
            for (int kt = 0; kt < 4; ++kt) whhR[o][kt] = ldw(Whh, 192, 64, 192, kt * 16, o * 16, lane);
        }
#pragma unroll
        for (int o = 0; o < 4; ++o) {
            W2L[(o * 2 + 0) * 64 + lane] = h2u(ldw(Wx1, 64, 24, 64, 0, o * 16, lane));
            W2L[(o * 2 + 1) * 64 + lane] = h2u(ldw(Wx1, 64, 24, 64, 16, o * 16, lane));
#pragma unroll
            for (int kt = 0; kt < 4; ++kt)
                W2L[(8 + o * 4 + kt) * 64 + lane] = h2u(ldw(Wx2, 64, 64, 64, kt * 16, o * 16, lane));
        }
        f32x4 B1[4], B2[4];
#pragma unroll
        for (int o = 0; o < 4; ++o) { B1[o] = ldb4(bx1, o, lgr); B2[o] = ldb4(bx2, o, lgr); }

        const float* xb_ = src + (size_t)(r0 + lcol) * TT * XD;
        f32x4 fx0 = *reinterpret_cast<const f32x4*>(xb_ + lgr * 4);
        f32x4 fx1 = Z4();
        if (lgr < 2) fx1 = *reinterpret_cast<const f32x4*>(xb_ + 16 + lgr * 4);

        // prologue: phi_x(0) -> PXB[0]; prefetch x(1)
        {
            half4 x0 = cvt4(fx0), x1 = cvt4(fx1);
            half4 axb[4], pxn[4];
#pragma unroll
            for (int o = 0; o < 4; ++o)
                axb[o] = cvt_relu(MFMA16(u2h(W2L[(o * 2 + 1) * 64 + lane]), x1,
                                  MFMA16(u2h(W2L[(o * 2 + 0) * 64 + lane]), x0, B1[o])));
#pragma unroll
            for (int o = 0; o < 4; ++o) {
                f32x4 a = B2[o];
#pragma unroll
                for (int kt = 0; kt < 4; ++kt) a = MFMA16(u2h(W2L[(8 + o * 4 + kt) * 64 + lane]), axb[kt], a);
                pxn[o] = cvt_relu(a);
            }
#pragma unroll
            for (int kt = 0; kt < 4; ++kt) PXB[0][kt * 64 + lane] = h2u(pxn[kt]);
        }
        fx0 = *reinterpret_cast<const f32x4*>(xb_ + XD + lgr * 4);
        fx1 = Z4();
        if (lgr < 2) fx1 = *reinterpret_cast<const f32x4*>(xb_ + XD + 16 + lgr * 4);
        __syncthreads();   // pre-loop

#pragma unroll 1
        for (int t = 0; t < TT; ++t) {
            int zz = 0;
            asm volatile("" : "+v"(zz));
            const int la = lane + zz;

            half4 hb[4];
#pragma unroll
            for (int kt = 0; kt < 4; ++kt) hb[kt] = u2h(HBUF[kt * 64 + lane]);
            f32x4 ga[4];
#pragma unroll
            for (int o = 0; o < 4; ++o) {
                f32x4 a = MFMA16(whhR[o][1], hb[1], MFMA16(whhR[o][0], hb[0], Z4()));
                f32x4 b = MFMA16(whhR[o][3], hb[3], MFMA16(whhR[o][2], hb[2], Z4()));
                ga[o] = a + b;
            }
            if (t + 1 < TT) {
                half4 x0 = cvt4(fx0), x1 = cvt4(fx1);
                half4 axb[4], pxn[4];
#pragma unroll
                for (int o = 0; o < 4; ++o)
                    axb[o] = cvt_relu(MFMA16(u2h(W2L[(o * 2 + 1) * 64 + la]), x1,
                                      MFMA16(u2h(W2L[(o * 2 + 0) * 64 + la]), x0, B1[o])));
#pragma unroll
                for (int o = 0; o < 4; ++o) {
                    f32x4 a = B2[o];
#pragma unroll
                    for (int kt = 0; kt < 4; ++kt) a = MFMA16(u2h(W2L[(8 + o * 4 + kt) * 64 + la]), axb[kt], a);
                    pxn[o] = cvt_relu(a);
                }
#pragma unroll
                for (int kt = 0; kt < 4; ++kt) PXB[(t + 1) & 1][kt * 64 + lane] = h2u(pxn[kt]);
                if (t + 2 < TT) {
                    fx0 = *reinterpret_cast<const f32x4*>(xb_ + (size_t)(t + 2) * XD + lgr * 4);
                    fx1 = Z4();
                    if (lgr < 2) fx1 = *reinterpret_cast<const f32x4*>(xb_ + (size_t)(t + 2) * XD + 16 + lgr * 4);
                }
            }
            __syncthreads();   // B
            half4 pb[8];
#pragma unroll
            for (int kt = 0; kt < 4; ++kt) pb[kt] = u2h(PXB[t & 1][kt * 64 + lane]);
#pragma unroll
            for (int kt = 0; kt < 4; ++kt) pb[4 + kt] = u2h(PZB[kt * 64 + lane]);
#pragma unroll
            for (int o = 0; o < 4; ++o) {
                f32x4 a = ga[o];
#pragma unroll
                for (int kt = 0; kt < 4; ++kt) a = MFMA16(wihR[o][kt], pb[kt], a);
                f32x4 b = Z4();
#pragma unroll
                for (int kt = 0; kt < 4; ++kt) b = MFMA16(wihR[o][4 + kt], pb[4 + kt], b);
                f32x4 s = a + b;
                f32x4 rv;
#pragma unroll
                for (int q = 0; q < 4; ++q) rv[q] = sigm(s[q]);
                RBUF[o * 64 + lane] = rv;
            }
            __syncthreads();   // C
            __syncthreads();   // D
        }

    } else {
        // ============ wave 3: n-gate + h owner (regs) ==================================
        half4 wihN[4][8], whhN[4][4];
#pragma unroll
        for (int o = 0; o < 4; ++o) {
#pragma unroll
            for (int kt = 0; kt < 8; ++kt) wihN[o][kt] = ldw(Wih, 192, 128, 192, kt * 16, 128 + o * 16, lane);
#pragma unroll
            for (int kt = 0; kt < 4; ++kt) whhN[o][kt] = ldw(Whh, 192, 64, 192, kt * 16, 128 + o * 16, lane);
        }
        f32x4 hD[4];
        half4 hb[4];
        half4 hz;
#pragma unroll
        for (int j = 0; j < 4; ++j) hz[j] = (_Float16)0.0f;
#pragma unroll
        for (int o = 0; o < 4; ++o) {
            hD[o] = Z4();
            hb[o] = hz;
            HBUF[o * 64 + lane] = h2u(hb[o]);
        }
        __syncthreads();   // pre-loop

#pragma unroll 1
        for (int t = 0; t < TT; ++t) {
            f32x4 gh[4];
#pragma unroll
            for (int o = 0; o < 4; ++o) {
                f32x4 a = MFMA16(whhN[o][1], hb[1], MFMA16(whhN[o][0], hb[0], Z4()));
                f32x4 b = MFMA16(whhN[o][3], hb[3], MFMA16(whhN[o][2], hb[2], Z4()));
                gh[o] = a + b;
            }
            __syncthreads();   // B
            half4 pb[8];
#pragma unroll
            for (int kt = 0; kt < 4; ++kt) pb[kt] = u2h(PXB[t & 1][kt * 64 + lane]);
#pragma unroll
            for (int kt = 0; kt < 4; ++kt) pb[4 + kt] = u2h(PZB[kt * 64 + lane]);
            f32x4 gi[4];
#pragma unroll
            for (int o = 0; o < 4; ++o) {
                f32x4 a = Z4();
#pragma unroll
                for (int kt = 0; kt < 4; ++kt) a = MFMA16(wihN[o][kt], pb[kt], a);
                f32x4 b = Z4();
#pragma unroll
                for (int kt = 0; kt < 4; ++kt) b = MFMA16(wihN[o][4 + kt], pb[4 + kt], b);
                gi[o] = a + b;
            }
            __syncthreads();   // C
#pragma unroll
            for (int o = 0; o < 4; ++o) {
                f32x4 rr = RBUF[o * 64 + lane];
                f32x4 uu = UBUF[o * 64 + lane];
#pragma unroll
                for (int q = 0; q < 4; ++q) {
                    float n = tanh_fast(gi[o][q] + rr[q] * gh[o][q]);
                    hD[o][q] = (1.0f - uu[q]) * n + uu[q] * hD[o][q];
                }
                hb[o] = cvt4(hD[o]);
                HBUF[o * 64 + lane] = h2u(hb[o]);
            }
            __syncthreads();   // D
        }
    }
}

extern "C" void kernel_launch(void* const* d_in, const int* in_sizes, int n_in,
                              void* d_out, int out_size, void* d_ws, size_t ws_size,
                              hipStream_t stream) {
    (void)in_sizes; (void)n_in; (void)d_ws; (void)ws_size; (void)out_size;
    const float* src = (const float*)d_in[0];
    const float* eps = (const float*)d_in[1];
    const float* Wx1 = (const float*)d_in[2];
    const float* bx1 = (const float*)d_in[3];
    const float* Wx2 = (const float*)d_in[4];
    const float* bx2 = (const float*)d_in[5];
    const float* Wz  = (const float*)d_in[6];
    const float* bz  = (const float*)d_in[7];
    const float* We1 = (const float*)d_in[8];
    const float* be1 = (const float*)d_in[9];
    const float* We2 = (const float*)d_in[10];
    const float* be2 = (const float*)d_in[11];
    const float* Wem = (const float*)d_in[12];
    const float* bem = (const float*)d_in[13];
    const float* Wes = (const float*)d_in[14];
    const float* bes = (const float*)d_in[15];
    const float* Wih = (const float*)d_in[16];
    const float* Whh = (const float*)d_in[17];
    const float* Wf1 = (const float*)d_in[18];
    const float* bf1 = (const float*)d_in[19];
    const float* Wf2 = (const float*)d_in[20];
    const float* bf2 = (const float*)d_in[21];
    const float* Wf3 = (const float*)d_in[22];
    const float* bf3 = (const float*)d_in[23];
    float* out = (float*)d_out;

    hipLaunchKernelGGL(vrnn_kernel, dim3(BB / 16), dim3(256), 0, stream,
                       src, eps, Wx1, bx1, Wx2, bx2, Wz, bz, We1, be1, We2, be2,
                       Wem, bem, Wes, bes, Wih, Whh, Wf1, bf1, Wf2, bf2, Wf3, bf3, out);
}

// Round 6
// 1250.571 us; speedup vs baseline: 1.5579x; 1.5579x over previous
//
#include <hip/hip_runtime.h>

#define TT 512
#define BB 1024
#define XD 24
#define ZD 16

typedef __attribute__((ext_vector_type(4))) _Float16 half4;
typedef __attribute__((ext_vector_type(4))) float f32x4;
typedef unsigned long long u64;

__device__ __forceinline__ f32x4 MFMA16(half4 a, half4 b, f32x4 c) {
#if defined(__HIP_DEVICE_COMPILE__)
    return __builtin_amdgcn_mfma_f32_16x16x16f16(a, b, c, 0, 0, 0);
#else
    return c;   // host pass only needs to parse
#endif
}

// Raw barrier: waits LDS ops only; global prefetch loads stay in flight (no vmcnt drain).
#define BAR() asm volatile("s_waitcnt lgkmcnt(0)\n\ts_barrier" ::: "memory")

__device__ __forceinline__ f32x4 Z4() { return (f32x4){0.f, 0.f, 0.f, 0.f}; }

__device__ __forceinline__ float sigm(float x) { return 1.0f / (1.0f + __expf(-x)); }

__device__ __forceinline__ float tanh_fast(float x) {
    return 1.0f - 2.0f / (1.0f + __expf(2.0f * x));   // saturates via inf/rcp
}

__device__ __forceinline__ float softplus_f(float x) {
    return fmaxf(x, 0.0f) + log1pf(__expf(-fabsf(x)));
}

// A-fragment of W^T (16 out-feats x 16 k). Lane l holds W[k0+(l>>4)*4+j][o0+(l&15)],
// zero-padded outside Kreal/Nreal. W row-major [K][N].
__device__ __forceinline__ half4 ldw(const float* W, int N, int Kreal, int Nreal,
                                     int k0, int o0, int lane) {
    int col = o0 + (lane & 15);
    int kb = k0 + ((lane >> 4) << 2);
    half4 r;
#pragma unroll
    for (int j = 0; j < 4; ++j) {
        int k = kb + j;
        float v = (k < Kreal && col < Nreal) ? W[(size_t)k * N + col] : 0.0f;
        r[j] = (_Float16)v;
    }
    return r;
}

__device__ __forceinline__ half4 cvt_relu(f32x4 a) {
    half4 r;
#pragma unroll
    for (int q = 0; q < 4; ++q) r[q] = (_Float16)fmaxf(a[q], 0.0f);
    return r;
}

__device__ __forceinline__ half4 cvt4(f32x4 a) {
    half4 r;
#pragma unroll
    for (int q = 0; q < 4; ++q) r[q] = (_Float16)a[q];
    return r;
}

__device__ __forceinline__ f32x4 ldb4(const float* b, int o, int lgr) {
    return *reinterpret_cast<const f32x4*>(b + o * 16 + lgr * 4);
}

__device__ __forceinline__ u64 h2u(half4 h) {
    union { half4 h; u64 u; } c; c.h = h; return c.u;
}
__device__ __forceinline__ half4 u2h(u64 u) {
    union { half4 h; u64 u; } c; c.u = u; return c.h;
}

__global__ __launch_bounds__(256, 1) void vrnn_kernel(
    const float* __restrict__ src, const float* __restrict__ eps,
    const float* __restrict__ Wx1, const float* __restrict__ bx1,
    const float* __restrict__ Wx2, const float* __restrict__ bx2,
    const float* __restrict__ Wz,  const float* __restrict__ bz,
    const float* __restrict__ We1, const float* __restrict__ be1,
    const float* __restrict__ We2, const float* __restrict__ be2,
    const float* __restrict__ Wem, const float* __restrict__ bem,
    const float* __restrict__ Wes, const float* __restrict__ bes,
    const float* __restrict__ Wih, const float* __restrict__ Whh,
    const float* __restrict__ Wf1, const float* __restrict__ bf1,
    const float* __restrict__ Wf2, const float* __restrict__ bf2,
    const float* __restrict__ Wf3, const float* __restrict__ bf3,
    float* __restrict__ out)
{
    // Activation exchange buffers, all in B-fragment form (8B/lane/frag)
    __shared__ u64 AXB[4 * 64];     // ax(t+1)
    __shared__ u64 A1B[4 * 64];     // a1(t)
    __shared__ u64 PZB[4 * 64];     // phi_z(t)
    __shared__ u64 HB[4 * 64];      // h
    __shared__ u64 PXB[2][4 * 64];  // phi_x, double-buffered

    const int tid = threadIdx.x;
    const int w = tid >> 6;       // wave id = o-tile slice
    const int lane = tid & 63;
    const int lcol = lane & 15;   // batch column
    const int lgr = lane >> 4;
    const int r0 = blockIdx.x * 16;
    const int o0w = w * 16;

    // ---------------- weights (registers, per-wave slices) ----------------
    half4 wx1f[2], wx2f[4], we1f[8], we2f[4][4], wemf[4], wesf[4], wzf;
    wx1f[0] = ldw(Wx1, 64, 24, 64, 0, o0w, lane);
    wx1f[1] = ldw(Wx1, 64, 24, 64, 16, o0w, lane);
#pragma unroll
    for (int kt = 0; kt < 4; ++kt) wx2f[kt] = ldw(Wx2, 64, 64, 64, kt * 16, o0w, lane);
#pragma unroll
    for (int kt = 0; kt < 8; ++kt) we1f[kt] = ldw(We1, 64, 128, 64, kt * 16, o0w, lane);
#pragma unroll
    for (int o = 0; o < 4; ++o)
#pragma unroll
        for (int kt = 0; kt < 4; ++kt) we2f[o][kt] = ldw(We2, 64, 64, 64, kt * 16, o * 16, lane);
#pragma unroll
    for (int kt = 0; kt < 4; ++kt) {
        wemf[kt] = ldw(Wem, 16, 64, 16, kt * 16, 0, lane);
        wesf[kt] = ldw(Wes, 16, 64, 16, kt * 16, 0, lane);
    }
    wzf = ldw(Wz, 64, 16, 64, 0, o0w, lane);
    half4 wihf[3][8], whhf[3][4];
#pragma unroll
    for (int g = 0; g < 3; ++g) {
#pragma unroll
        for (int kt = 0; kt < 8; ++kt) wihf[g][kt] = ldw(Wih, 192, 128, 192, kt * 16, g * 64 + o0w, lane);
#pragma unroll
        for (int kt = 0; kt < 4; ++kt) whhf[g][kt] = ldw(Whh, 192, 64, 192, kt * 16, g * 64 + o0w, lane);
    }
    const f32x4 B1 = ldb4(bx1, w, lgr), B2 = ldb4(bx2, w, lgr);
    const f32x4 BE1 = ldb4(be1, w, lgr), BZ = ldb4(bz, w, lgr);
    f32x4 BE2[4];
#pragma unroll
    for (int o = 0; o < 4; ++o) BE2[o] = ldb4(be2, o, lgr);
    const f32x4 BM = ldb4(bem, 0, lgr), BS = ldb4(bes, 0, lgr);

    const float* xb_ = src + (size_t)(r0 + lcol) * TT * XD;
    const float* eb_ = eps + (size_t)(r0 + lcol) * TT * ZD;

    // ---------------- prologue: phi_x(0) -> PXB[0]; h = 0 ----------------
    f32x4 fx0 = *reinterpret_cast<const f32x4*>(xb_ + lgr * 4);
    f32x4 fx1 = Z4();
    if (lgr < 2) fx1 = *reinterpret_cast<const f32x4*>(xb_ + 16 + lgr * 4);
    {
        half4 x0 = cvt4(fx0), x1 = cvt4(fx1);
        f32x4 a = MFMA16(wx1f[1], x1, MFMA16(wx1f[0], x0, B1));
        AXB[w * 64 + lane] = h2u(cvt_relu(a));
    }
    HB[w * 64 + lane] = 0ull;
    f32x4 hD = Z4();
    BAR();
    {
        half4 axb[4];
#pragma unroll
        for (int kt = 0; kt < 4; ++kt) axb[kt] = u2h(AXB[kt * 64 + lane]);
        f32x4 a = B2;
#pragma unroll
        for (int kt = 0; kt < 4; ++kt) a = MFMA16(wx2f[kt], axb[kt], a);
        PXB[0][w * 64 + lane] = h2u(cvt_relu(a));
    }
    // prefetch x(1), eps(0) — will stay in flight across raw barriers
    fx0 = *reinterpret_cast<const f32x4*>(xb_ + XD + lgr * 4);
    fx1 = Z4();
    if (lgr < 2) fx1 = *reinterpret_cast<const f32x4*>(xb_ + XD + 16 + lgr * 4);
    f32x4 fe = *reinterpret_cast<const f32x4*>(eb_ + lgr * 4);
    BAR();

    f32x4 pzlast = Z4();
    half4 pxb[4], pzbL[4];

#pragma unroll 1
    for (int t = 0; t < TT; ++t) {
        // ================= P1: s3 + gh + s1(t+1) =================
        half4 hb[4];
#pragma unroll
        for (int kt = 0; kt < 4; ++kt) hb[kt] = u2h(HB[kt * 64 + lane]);
#pragma unroll
        for (int kt = 0; kt < 4; ++kt) pxb[kt] = u2h(PXB[t & 1][kt * 64 + lane]);

        {   // s3: a1 o-tile w
            f32x4 a = BE1;
#pragma unroll
            for (int kt = 0; kt < 4; ++kt) a = MFMA16(we1f[kt], pxb[kt], a);
            f32x4 b = Z4();
#pragma unroll
            for (int kt = 0; kt < 4; ++kt) b = MFMA16(we1f[4 + kt], hb[kt], b);
            A1B[w * 64 + lane] = h2u(cvt_relu(a + b));
        }
        f32x4 ga[3];
#pragma unroll
        for (int g = 0; g < 3; ++g) {   // gh for r,u,n (col-slice w)
            f32x4 a = MFMA16(whhf[g][1], hb[1], MFMA16(whhf[g][0], hb[0], Z4()));
            f32x4 b = MFMA16(whhf[g][3], hb[3], MFMA16(whhf[g][2], hb[2], Z4()));
            ga[g] = a + b;
        }
        if (t + 1 < TT) {   // s1(t+1)
            half4 x0 = cvt4(fx0), x1 = cvt4(fx1);
            f32x4 s = MFMA16(wx1f[1], x1, MFMA16(wx1f[0], x0, B1));
            AXB[w * 64 + lane] = h2u(cvt_relu(s));
            if (t + 2 < TT) {
                fx0 = *reinterpret_cast<const f32x4*>(xb_ + (size_t)(t + 2) * XD + lgr * 4);
                fx1 = Z4();
                if (lgr < 2) fx1 = *reinterpret_cast<const f32x4*>(xb_ + (size_t)(t + 2) * XD + 16 + lgr * 4);
            }
        }
        BAR();

        // ================= P2: s4(redundant) + s5 + z + s6 + s2(t+1) =================
        half4 a1b[4];
#pragma unroll
        for (int kt = 0; kt < 4; ++kt) a1b[kt] = u2h(A1B[kt * 64 + lane]);
        half4 enb[4];
#pragma unroll
        for (int o = 0; o < 4; ++o) {
            f32x4 p = MFMA16(we2f[o][1], a1b[1], MFMA16(we2f[o][0], a1b[0], BE2[o]));
            f32x4 q = MFMA16(we2f[o][3], a1b[3], MFMA16(we2f[o][2], a1b[2], Z4()));
            enb[o] = cvt_relu(p + q);
        }
        f32x4 am = MFMA16(wemf[1], enb[1], MFMA16(wemf[0], enb[0], BM));
        f32x4 am2 = MFMA16(wemf[3], enb[3], MFMA16(wemf[2], enb[2], Z4()));
        f32x4 as_ = MFMA16(wesf[1], enb[1], MFMA16(wesf[0], enb[0], BS));
        f32x4 as2 = MFMA16(wesf[3], enb[3], MFMA16(wesf[2], enb[2], Z4()));
        f32x4 eC = fe;
        if (t + 1 < TT) fe = *reinterpret_cast<const f32x4*>(eb_ + (size_t)(t + 1) * ZD + lgr * 4);
        f32x4 zD;
#pragma unroll
        for (int q = 0; q < 4; ++q)
            zD[q] = eC[q] * softplus_f(as_[q] + as2[q]) + (am[q] + am2[q]);
        half4 zb = cvt4(zD);
        {   // s6: phi_z o-tile w
            f32x4 a = MFMA16(wzf, zb, BZ);
            if (t == TT - 1) {
#pragma unroll
                for (int q = 0; q < 4; ++q) pzlast[q] = fmaxf(a[q], 0.0f);
            }
            PZB[w * 64 + lane] = h2u(cvt_relu(a));
        }
        if (t + 1 < TT) {   // s2(t+1)
            half4 axb[4];
#pragma unroll
            for (int kt = 0; kt < 4; ++kt) axb[kt] = u2h(AXB[kt * 64 + lane]);
            f32x4 s = B2;
#pragma unroll
            for (int kt = 0; kt < 4; ++kt) s = MFMA16(wx2f[kt], axb[kt], s);
            PXB[(t + 1) & 1][w * 64 + lane] = h2u(cvt_relu(s));
        }
        BAR();

        // ================= P3: GRU gates + h update (col-slice w local) =================
#pragma unroll
        for (int kt = 0; kt < 4; ++kt) pzbL[kt] = u2h(PZB[kt * 64 + lane]);
        f32x4 gi[3];
#pragma unroll
        for (int g = 0; g < 3; ++g) {
            f32x4 p = (g < 2) ? ga[g] : Z4();
#pragma unroll
            for (int kt = 0; kt < 4; ++kt) p = MFMA16(wihf[g][kt], pxb[kt], p);
            f32x4 q = Z4();
#pragma unroll
            for (int kt = 0; kt < 4; ++kt) q = MFMA16(wihf[g][4 + kt], pzbL[kt], q);
            gi[g] = p + q;
        }
#pragma unroll
        for (int q = 0; q < 4; ++q) {
            float rr = sigm(gi[0][q]);
            float uu = sigm(gi[1][q]);
            float nn = tanh_fast(gi[2][q] + rr * ga[2][q]);
            hD[q] = (1.0f - uu) * nn + uu * hD[q];
        }
        HB[w * 64 + lane] = h2u(cvt4(hD));
        BAR();
    }

    // ---------------- outputs ----------------
    // phi_z(T-1) f32 slice per wave
    float* po = out + BB + (size_t)(r0 + lcol) * 64;
    *reinterpret_cast<f32x4*>(po + o0w + lgr * 4) = pzlast;

    // regressor head (wave 0 only, register-chained)
    if (w == 0) {
        half4 wf1t[4][4], wf2t[2][4], wf3t[2];
#pragma unroll
        for (int o = 0; o < 4; ++o)
#pragma unroll
            for (int kt = 0; kt < 4; ++kt) wf1t[o][kt] = ldw(Wf1, 64, 64, 64, kt * 16, o * 16, lane);
#pragma unroll
        for (int o = 0; o < 2; ++o)
#pragma unroll
            for (int kt = 0; kt < 4; ++kt) wf2t[o][kt] = ldw(Wf2, 32, 64, 32, kt * 16, o * 16, lane);
        wf3t[0] = ldw(Wf3, 1, 32, 1, 0, 0, lane);
        wf3t[1] = ldw(Wf3, 1, 32, 1, 16, 0, lane);

        half4 o1b[4];
#pragma unroll
        for (int o = 0; o < 4; ++o) {
            f32x4 a = ldb4(bf1, o, lgr);
#pragma unroll
            for (int kt = 0; kt < 4; ++kt) a = MFMA16(wf1t[o][kt], pzbL[kt], a);
            o1b[o] = cvt_relu(a);
        }
        half4 o2b[2];
#pragma unroll
        for (int o = 0; o < 2; ++o) {
            f32x4 a = ldb4(bf2, o, lgr);
#pragma unroll
            for (int kt = 0; kt < 4; ++kt) a = MFMA16(wf2t[o][kt], o1b[kt], a);
            o2b[o] = cvt_relu(a);
        }
        float b3 = bf3[0];
        f32x4 p = (f32x4){b3, b3, b3, b3};
        p = MFMA16(wf3t[0], o2b[0], p);
        p = MFMA16(wf3t[1], o2b[1], p);
        if (lgr == 0) out[r0 + lcol] = p[0];
    }
}

extern "C" void kernel_launch(void* const* d_in, const int* in_sizes, int n_in,
                              void* d_out, int out_size, void* d_ws, size_t ws_size,
                              hipStream_t stream) {
    (void)in_sizes; (void)n_in; (void)d_ws; (void)ws_size; (void)out_size;
    const float* src = (const float*)d_in[0];
    const float* eps = (const float*)d_in[1];
    const float* Wx1 = (const float*)d_in[2];
    const float* bx1 = (const float*)d_in[3];
    const float* Wx2 = (const float*)d_in[4];
    const float* bx2 = (const float*)d_in[5];
    const float* Wz  = (const float*)d_in[6];
    const float* bz  = (const float*)d_in[7];
    const float* We1 = (const float*)d_in[8];
    const float* be1 = (const float*)d_in[9];
    const float* We2 = (const float*)d_in[10];
    const float* be2 = (const float*)d_in[11];
    const float* Wem = (const float*)d_in[12];
    const float* bem = (const float*)d_in[13];
    const float* Wes = (const float*)d_in[14];
    const float* bes = (const float*)d_in[15];
    const float* Wih = (const float*)d_in[16];
    const float* Whh = (const float*)d_in[17];
    const float* Wf1 = (const float*)d_in[18];
    const float* bf1 = (const float*)d_in[19];
    const float* Wf2 = (const float*)d_in[20];
    const float* bf2 = (const float*)d_in[21];
    const float* Wf3 = (const float*)d_in[22];
    const float* bf3 = (const float*)d_in[23];
    float* out = (float*)d_out;

    hipLaunchKernelGGL(vrnn_kernel, dim3(BB / 16), dim3(256), 0, stream,
                       src, eps, Wx1, bx1, Wx2, bx2, Wz, bz, We1, be1, We2, be2,
                       Wem, bem, Wes, bes, Wih, Whh, Wf1, bf1, Wf2, bf2, Wf3, bf3, out);
}